// Round 3
// baseline (266.630 us; speedup 1.0000x reference)
//
#include <hip/hip_runtime.h>

// ---------------------------------------------------------------------------
// ActorCritic fused loss, MI355X.  T=8192, B=4096.
//   k_detect : mask dtype probe (int32 {0,1} vs 1-byte bool)
//   k_scan   : rewards -> chunk-local discounted sums S[NC][B]   (2048 blocks)
//   k_fold   : S -> 32 group aggregates Sg[32][B]                (128 blocks)
//   k_gscan  : Sg -> group-entry carries Hg[32][B]               (4 blocks, 32 iters)
//   k_main   : prologue reconstructs chunk carry from Hg + <=15 S reads, then
//              software-pipelined fused pass over all 5 inputs -> 10 sums.
//   k_final  : closed-form losses from the 10 sums.
// ---------------------------------------------------------------------------

constexpr int T   = 8192;
constexpr int B   = 4096;
constexpr int B4  = B / 4;          // 1024 float4 columns
constexpr int BLK = 256;
constexpr int WAVES = BLK / 64;
constexpr int L   = 16;             // chunk length
constexpr int NC  = T / L;          // 512 chunks
constexpr int NG  = 16;             // chunks per group
constexpr int NGR = NC / NG;        // 32 groups
constexpr int NB1 = NC * B4 / BLK;  // 2048 blocks for scan/main

constexpr float GAMMA_F = 0.99f;
constexpr double cpow(double g, int n) { double r = 1.0; for (int i = 0; i < n; ++i) r *= g; return r; }
constexpr float GL  = (float)cpow(0.99, L);       // gamma^16
constexpr float GLG = (float)cpow(0.99, L * NG);  // gamma^256

// --------------------------------------------------------------------------
__global__ void __launch_bounds__(BLK) k_detect(const unsigned char* __restrict__ m,
                                                int* __restrict__ flag) {
    __shared__ unsigned sh[WAVES];
    unsigned v = 0;
    for (int i = threadIdx.x; i < 65536; i += BLK)
        if (i & 3) v |= m[i];
    #pragma unroll
    for (int off = 32; off; off >>= 1) v |= __shfl_down(v, off);
    if ((threadIdx.x & 63) == 0) sh[threadIdx.x >> 6] = v;
    __syncthreads();
    if (threadIdx.x == 0) {
        unsigned r = 0;
        #pragma unroll
        for (int w = 0; w < WAVES; ++w) r |= sh[w];
        *flag = (r == 0) ? 1 : 0;   // 1 => int32 layout
    }
}

// --------------------------------------------------------------------------
#define ACC4(A_, R_)                         \
    do {                                     \
        A_.x = fmaf(GAMMA_F, A_.x, R_.x);    \
        A_.y = fmaf(GAMMA_F, A_.y, R_.y);    \
        A_.z = fmaf(GAMMA_F, A_.z, R_.z);    \
        A_.w = fmaf(GAMMA_F, A_.w, R_.w);    \
    } while (0)

// chunk-local discounted sums, 2-stage pipelined
__global__ void __launch_bounds__(BLK) k_scan(const float4* __restrict__ rw,
                                              float4* __restrict__ S) {
    int idx = blockIdx.x * BLK + threadIdx.x;
    int c = idx / B4;
    int b = idx - c * B4;
    const float4* p = rw + (size_t)c * L * B4 + b;
    float4 a = make_float4(0.f, 0.f, 0.f, 0.f);
    float4 rA = p[(L - 1) * B4];
    float4 rB = p[(L - 2) * B4];
    #pragma unroll
    for (int i = L - 1; i >= 3; i -= 2) {
        ACC4(a, rA);
        rA = p[(i - 2) * B4];
        ACC4(a, rB);
        rB = p[(i - 3) * B4];
    }
    ACC4(a, rA);
    ACC4(a, rB);
    S[idx] = a;
}

// --------------------------------------------------------------------------
#define FOLD4(H_, S_, W_)                    \
    do {                                     \
        H_.x = fmaf(W_, H_.x, S_.x);         \
        H_.y = fmaf(W_, H_.y, S_.y);         \
        H_.z = fmaf(W_, H_.z, S_.z);         \
        H_.w = fmaf(W_, H_.w, S_.w);         \
    } while (0)

// Sg[g] = sum_j gamma^(jL) S[g*NG+j]
__global__ void __launch_bounds__(BLK) k_fold(const float4* __restrict__ S4,
                                              float4* __restrict__ Sg4) {
    int tid = blockIdx.x * BLK + threadIdx.x;   // 0 .. NGR*B4-1
    int g = tid / B4;
    int b = tid - g * B4;
    float4 h = make_float4(0.f, 0.f, 0.f, 0.f);
    #pragma unroll 4
    for (int j = NG - 1; j >= 0; --j) {
        float4 s = S4[(size_t)(g * NG + j) * B4 + b];
        FOLD4(h, s, GL);
    }
    Sg4[tid] = h;
}

// Hg[g] = carry entering the END of group g (from groups > g)
__global__ void __launch_bounds__(BLK) k_gscan(const float4* __restrict__ Sg4,
                                               float4* __restrict__ Hg4) {
    int b = blockIdx.x * BLK + threadIdx.x;     // 0..B4-1
    float4 h = make_float4(0.f, 0.f, 0.f, 0.f);
    #pragma unroll 8
    for (int g = NGR - 1; g >= 0; --g) {
        Hg4[(size_t)g * B4 + b] = h;
        float4 s = Sg4[(size_t)g * B4 + b];
        FOLD4(h, s, GLG);
    }
}

// --------------------------------------------------------------------------
#define COMP(MJ, GX, RX, VX, LX, ZX)                 \
    do {                                             \
        GX = fmaf(GAMMA_F, GX, RX);                  \
        float mm = (MJ);                             \
        float Gm = mm * GX, vm = mm * VX, lm = mm * LX; \
        a[0] += mm; a[1] += Gm;                      \
        a[2] = fmaf(Gm, GX, a[2]);                   \
        a[3] = fmaf(Gm, VX, a[3]);                   \
        a[4] += vm; a[5] = fmaf(vm, VX, a[5]);       \
        a[6] = fmaf(lm, GX, a[6]); a[7] += lm;       \
        a[8] = fmaf(mm, ZX, a[8]);                   \
        a[9] = fmaf(lm, VX, a[9]);                   \
    } while (0)

#define PIPE_LOAD(S_, I_)                                                    \
    do {                                                                     \
        int e_ = base + (I_) * B4;                                           \
        r##S_ = rw[e_]; v##S_ = vv[e_]; l##S_ = lq[e_]; z##S_ = en[e_];      \
        if constexpr (I32) { q##S_ = ((const int4*)mp)[e_]; }                \
        else { uchar4 u_ = ((const uchar4*)mp)[e_];                          \
               q##S_ = make_int4(u_.x, u_.y, u_.z, u_.w); }                  \
    } while (0)

#define PIPE_COMP(S_)                                                        \
    do {                                                                     \
        COMP((q##S_.x ? 1.f : 0.f), G.x, r##S_.x, v##S_.x, l##S_.x, z##S_.x);\
        COMP((q##S_.y ? 1.f : 0.f), G.y, r##S_.y, v##S_.y, l##S_.y, z##S_.y);\
        COMP((q##S_.z ? 1.f : 0.f), G.z, r##S_.z, v##S_.z, l##S_.z, z##S_.z);\
        COMP((q##S_.w ? 1.f : 0.f), G.w, r##S_.w, v##S_.w, l##S_.w, z##S_.w);\
    } while (0)

template<bool I32>
__device__ __forceinline__ void main_body(const float4* __restrict__ rw,
                                          const float4* __restrict__ vv,
                                          const float4* __restrict__ lq,
                                          const float4* __restrict__ en,
                                          const void*  __restrict__ mp,
                                          int base, float4& G, float a[10]) {
    float4 rA, vA, lA, zA, rB, vB, lB, zB;
    int4 qA, qB;
    PIPE_LOAD(A, L - 1);
    PIPE_LOAD(B, L - 2);
    #pragma unroll
    for (int i = L - 1; i >= 3; i -= 2) {
        PIPE_COMP(A);
        PIPE_LOAD(A, i - 2);
        PIPE_COMP(B);
        PIPE_LOAD(B, i - 3);
    }
    PIPE_COMP(A);   // row 1
    PIPE_COMP(B);   // row 0
}

__global__ void __launch_bounds__(BLK) k_main(const float4* __restrict__ rw,
                                              const float4* __restrict__ vv,
                                              const float4* __restrict__ lq,
                                              const float4* __restrict__ en,
                                              const void*  __restrict__ mp,
                                              const int*   __restrict__ flag,
                                              const float4* __restrict__ S4,
                                              const float4* __restrict__ Hg4,
                                              double* __restrict__ partials) {
    int idx = blockIdx.x * BLK + threadIdx.x;
    int c = idx / B4;
    int b = idx - c * B4;
    int g = c / NG;
    int base = c * L * B4 + b;

    // prologue: chunk-entry carry H_c = fold(S[c+1 .. group end]) + Hg[g]
    float4 h = Hg4[(size_t)g * B4 + b];
    for (int k = g * NG + NG - 1; k > c; --k) {
        float4 s = S4[(size_t)k * B4 + b];
        FOLD4(h, s, GL);
    }
    float4 G = h;

    float a[10] = {0.f, 0.f, 0.f, 0.f, 0.f, 0.f, 0.f, 0.f, 0.f, 0.f};
    if (*flag) main_body<true >(rw, vv, lq, en, mp, base, G, a);
    else       main_body<false>(rw, vv, lq, en, mp, base, G, a);

    // deterministic block reduction in f64
    double d[10];
    #pragma unroll
    for (int k = 0; k < 10; ++k) d[k] = (double)a[k];
    #pragma unroll
    for (int k = 0; k < 10; ++k)
        #pragma unroll
        for (int off = 32; off; off >>= 1)
            d[k] += __shfl_down(d[k], off);

    __shared__ double sh[WAVES][10];
    int lane = threadIdx.x & 63, wv = threadIdx.x >> 6;
    if (lane == 0) {
        #pragma unroll
        for (int k = 0; k < 10; ++k) sh[wv][k] = d[k];
    }
    __syncthreads();
    if (threadIdx.x == 0) {
        #pragma unroll
        for (int k = 0; k < 10; ++k) {
            double s = sh[0][k];
            #pragma unroll
            for (int ww = 1; ww < WAVES; ++ww) s += sh[ww][k];
            partials[(size_t)blockIdx.x * 10 + k] = s;
        }
    }
}

// --------------------------------------------------------------------------
__global__ void __launch_bounds__(BLK) k_final(const double* __restrict__ partials,
                                               float* __restrict__ out) {
    double d[10];
    #pragma unroll
    for (int k = 0; k < 10; ++k) d[k] = 0.0;
    for (int i = threadIdx.x; i < NB1; i += BLK) {
        #pragma unroll
        for (int k = 0; k < 10; ++k) d[k] += partials[(size_t)i * 10 + k];
    }
    #pragma unroll
    for (int k = 0; k < 10; ++k)
        #pragma unroll
        for (int off = 32; off; off >>= 1)
            d[k] += __shfl_down(d[k], off);

    __shared__ double sh[WAVES][10];
    int lane = threadIdx.x & 63, wv = threadIdx.x >> 6;
    if (lane == 0) {
        #pragma unroll
        for (int k = 0; k < 10; ++k) sh[wv][k] = d[k];
    }
    __syncthreads();
    if (threadIdx.x == 0) {
        double s[10];
        #pragma unroll
        for (int k = 0; k < 10; ++k) {
            double t = sh[0][k];
            #pragma unroll
            for (int ww = 1; ww < WAVES; ++ww) t += sh[ww][k];
            s[k] = t;
        }
        double n = s[0], SG = s[1], SG2 = s[2], SGv = s[3], Sv = s[4];
        double Sv2 = s[5], SlpG = s[6], Slp = s[7], Sent = s[8], Slpv = s[9];

        double mean = SG / n;
        double css  = SG2 - 2.0 * mean * SG + mean * mean * n;  // sum m*(G-mean)^2
        double var  = css / (n - 1.0);
        double sd   = sqrt(var);
        double sc   = 1.0 / (sd + 1e-8);

        double critic = sc * sc * css - 2.0 * sc * (SGv - mean * Sv) + Sv2;
        double actor  = -sc * (SlpG - mean * Slp) + Slpv - 0.01 * Sent;

        out[0] = (float)critic;
        out[1] = (float)actor;
    }
}

// --------------------------------------------------------------------------
extern "C" void kernel_launch(void* const* d_in, const int* in_sizes, int n_in,
                              void* d_out, int out_size, void* d_ws, size_t ws_size,
                              hipStream_t stream) {
    const float4* rw = (const float4*)d_in[0];
    const float4* vv = (const float4*)d_in[1];
    const float4* lq = (const float4*)d_in[2];
    const float4* en = (const float4*)d_in[3];
    const void*   mp = d_in[4];

    char* ws = (char*)d_ws;
    size_t off = 0;
    float4* S  = (float4*)(ws + off); off += (size_t)NC  * B4 * 16;  // 8 MiB
    float4* Sg = (float4*)(ws + off); off += (size_t)NGR * B4 * 16;  // 512 KiB
    float4* Hg = (float4*)(ws + off); off += (size_t)NGR * B4 * 16;  // 512 KiB
    double* p1 = (double*)(ws + off); off += (size_t)NB1 * 10 * 8;   // 160 KiB
    int*  flag = (int*)  (ws + off);

    k_detect<<<1, BLK, 0, stream>>>((const unsigned char*)mp, flag);
    k_scan  <<<NB1, BLK, 0, stream>>>(rw, S);
    k_fold  <<<NGR * B4 / BLK, BLK, 0, stream>>>(S, Sg);
    k_gscan <<<B4 / BLK, BLK, 0, stream>>>(Sg, Hg);
    k_main  <<<NB1, BLK, 0, stream>>>(rw, vv, lq, en, mp, flag, S, Hg, p1);
    k_final <<<1, BLK, 0, stream>>>(p1, (float*)d_out);
}